// Round 2
// baseline (6958.948 us; speedup 1.0000x reference)
//
#include <hip/hip_runtime.h>
#include <hip/hip_bf16.h>
#include <hip/hip_fp16.h>
#include <math.h>

#define BB 64
#define SS 512
#define TT 48
#define EE 300
#define EP 320   // E padded to multiple of 16
#define HH 256
#define G4 1024  // 4*H
#define NG 2048  // both directions
#define NEGV -10000.0f

__device__ __forceinline__ float sigf(float x) { return 1.0f / (1.0f + __expf(-x)); }

__device__ __forceinline__ float4 ld_half4(const __half* p) {
    union { float2 f2; __half2 h2[2]; } u;
    u.f2 = *(const float2*)p;                 // one 8-byte load
    float2 a = __half22float2(u.h2[0]);
    float2 b = __half22float2(u.h2[1]);
    return make_float4(a.x, a.y, b.x, b.y);
}
__device__ __forceinline__ void st_half4(__half* p, float4 v) {
    union { float2 f2; __half2 h2[2]; } u;
    u.h2[0] = __floats2half2_rn(v.x, v.y);
    u.h2[1] = __floats2half2_rn(v.z, v.w);
    *(float2*)p = u.f2;                       // one 8-byte store
}

// ---------------- prep: transposes + fused bias (fp16 weight copies) -------
// WTF/WTB: [H][4H] fp16 (WhhT per dir)
// WIHT:    [EP][NG] fp16 (WihT, dirs concat on N, zero-padded K)
// BIAS:    [NG] fp32 (bih+bhh per dir)
// WOT:     [512][T] fp32 (W_out transposed)
__global__ __launch_bounds__(256) void k_prep(
    const float* __restrict__ Whh_f, const float* __restrict__ Whh_b,
    const float* __restrict__ Wih_f, const float* __restrict__ Wih_b,
    const float* __restrict__ bih_f, const float* __restrict__ bhh_f,
    const float* __restrict__ bih_b, const float* __restrict__ bhh_b,
    const float* __restrict__ W_out,
    __half* __restrict__ WTF, __half* __restrict__ WTB,
    __half* __restrict__ WIHT, float* __restrict__ BIAS, float* __restrict__ WOT)
{
    int i = blockIdx.x * 256 + threadIdx.x;
    const int NWHH = HH * G4;      // 262144
    if (i < NWHH) { int k = i / G4, g = i % G4; WTF[i] = __float2half(Whh_f[g * HH + k]); return; }
    i -= NWHH;
    if (i < NWHH) { int k = i / G4, g = i % G4; WTB[i] = __float2half(Whh_b[g * HH + k]); return; }
    i -= NWHH;
    const int NWIH = EP * NG;      // 655360
    if (i < NWIH) {
        int k = i / NG, n = i % NG; int d = n >> 10, g = n & 1023;
        const float* w = d ? Wih_b : Wih_f;
        WIHT[i] = __float2half((k < EE) ? w[g * EE + k] : 0.0f);
        return;
    }
    i -= NWIH;
    if (i < NG) {
        int d = i >> 10, g = i & 1023;
        BIAS[i] = d ? (bih_b[g] + bhh_b[g]) : (bih_f[g] + bhh_f[g]);
        return;
    }
    i -= NG;
    if (i < 512 * TT) { int k = i / TT, t = i % TT; WOT[i] = W_out[t * 512 + k]; return; }
}

// ---------------- embedding gather + concat + pad ----------------
// X: [S*B][EP] fp16, row sb = s*64+b
__global__ __launch_bounds__(320) void k_embed(
    const int* __restrict__ wid, const int* __restrict__ fid, const int* __restrict__ pid,
    const float* __restrict__ ew, const float* __restrict__ ef, const float* __restrict__ ep,
    __half* __restrict__ X)
{
    int sb = blockIdx.x; int s = sb >> 6, b = sb & 63;
    int t = threadIdx.x;
    int w = wid[b * SS + s];
    int f = fid[b * SS + s];
    int p = pid[b * SS + s];
    float v;
    if (t < 200)      v = ew[w * 200 + t];
    else if (t < 250) v = ef[f * 50 + (t - 200)];
    else if (t < 300) v = ep[p * 50 + (t - 250)];
    else              v = 0.0f;
    X[(size_t)sb * EP + t] = __float2half(v);
}

// ---------------- input GEMM: GX[32768][2048] = X * WIHT + BIAS (fp16 io) --
__global__ __launch_bounds__(256) void k_gemm(
    const __half* __restrict__ X, const __half* __restrict__ WIHT,
    const float* __restrict__ BIAS, __half* __restrict__ GX)
{
    __shared__ float Al[16][64];   // [k][m]
    __shared__ float Bl[16][64];   // [k][n]
    int tid = threadIdx.x;
    int tx = tid & 15, ty = tid >> 4;
    int m0 = blockIdx.y * 64, n0 = blockIdx.x * 64;
    float acc[4][4] = {};
    for (int k0 = 0; k0 < EP; k0 += 16) {
        int r = tid >> 2, q = tid & 3;
        float4 a4 = ld_half4(X + (size_t)(m0 + r) * EP + k0 + 4 * q);
        Al[4 * q + 0][r] = a4.x; Al[4 * q + 1][r] = a4.y;
        Al[4 * q + 2][r] = a4.z; Al[4 * q + 3][r] = a4.w;
        int kk = tid >> 4, c = (tid & 15) * 4;
        float4 b4 = ld_half4(WIHT + (size_t)(k0 + kk) * NG + n0 + c);
        *(float4*)&Bl[kk][c] = b4;
        __syncthreads();
        #pragma unroll
        for (int k = 0; k < 16; k++) {
            float4 a = *(const float4*)&Al[k][ty * 4];
            float4 b = *(const float4*)&Bl[k][tx * 4];
            acc[0][0] += a.x * b.x; acc[0][1] += a.x * b.y; acc[0][2] += a.x * b.z; acc[0][3] += a.x * b.w;
            acc[1][0] += a.y * b.x; acc[1][1] += a.y * b.y; acc[1][2] += a.y * b.z; acc[1][3] += a.y * b.w;
            acc[2][0] += a.z * b.x; acc[2][1] += a.z * b.y; acc[2][2] += a.z * b.z; acc[2][3] += a.z * b.w;
            acc[3][0] += a.w * b.x; acc[3][1] += a.w * b.y; acc[3][2] += a.w * b.z; acc[3][3] += a.w * b.w;
        }
        __syncthreads();
    }
    float4 bias = *(const float4*)(BIAS + n0 + tx * 4);
    #pragma unroll
    for (int i = 0; i < 4; i++) {
        float4 st;
        st.x = acc[i][0] + bias.x; st.y = acc[i][1] + bias.y;
        st.z = acc[i][2] + bias.z; st.w = acc[i][3] + bias.w;
        st_half4(GX + (size_t)(m0 + ty * 4 + i) * NG + n0 + tx * 4, st);
    }
}

// ---------------- recurrent LSTM: one wg per (dir, batch) ----------------
// HS: [S*B][2H] fp16, forward cols [0,256), backward [256,512)
__global__ __launch_bounds__(256) void k_lstm(
    const __half* __restrict__ GX, const __half* __restrict__ WTF,
    const __half* __restrict__ WTB, const float* __restrict__ h0,
    const float* __restrict__ c0, __half* __restrict__ HS)
{
    int wg = blockIdx.x;
    int dir = wg >> 6, b = wg & 63;
    int tid = threadIdx.x;
    const __half* wt = dir ? WTB : WTF;
    __shared__ float hl[HH];
    __shared__ float gl[G4];
    hl[tid] = h0[(size_t)dir * BB * HH + b * HH + tid];
    float c = c0[(size_t)dir * BB * HH + b * HH + tid];
    __syncthreads();
    for (int t = 0; t < SS; t++) {
        int s = dir ? (SS - 1 - t) : t;
        const __half* gxr = GX + (size_t)(s * BB + b) * NG + dir * G4 + 4 * tid;
        float4 acc = ld_half4(gxr);
        #pragma unroll 4
        for (int k = 0; k < HH; k += 4) {
            float4 hk = *(const float4*)&hl[k];
            const __half* wp = wt + (size_t)k * G4 + 4 * tid;
            float4 w0 = ld_half4(wp);
            float4 w1 = ld_half4(wp + G4);
            float4 w2 = ld_half4(wp + 2 * G4);
            float4 w3 = ld_half4(wp + 3 * G4);
            acc.x += hk.x * w0.x + hk.y * w1.x + hk.z * w2.x + hk.w * w3.x;
            acc.y += hk.x * w0.y + hk.y * w1.y + hk.z * w2.y + hk.w * w3.y;
            acc.z += hk.x * w0.z + hk.y * w1.z + hk.z * w2.z + hk.w * w3.z;
            acc.w += hk.x * w0.w + hk.y * w1.w + hk.z * w2.w + hk.w * w3.w;
        }
        *(float4*)&gl[4 * tid] = acc;
        __syncthreads();
        float gi = gl[tid], gf = gl[HH + tid], gg = gl[2 * HH + tid], go = gl[3 * HH + tid];
        c = sigf(gf) * c + sigf(gi) * tanhf(gg);
        float h = sigf(go) * tanhf(c);
        hl[tid] = h;
        HS[(size_t)(s * BB + b) * (2 * HH) + dir * HH + tid] = __float2half(h);
        __syncthreads();
    }
}

// ---------------- feats: [32768][48] = HS * WOT + b_out --------------------
__global__ __launch_bounds__(384) void k_feats(
    const __half* __restrict__ HS, const float* __restrict__ WOT,
    const float* __restrict__ b_out, float* __restrict__ F)
{
    __shared__ float rl[8 * 512];
    int sb0 = blockIdx.x * 8;
    int tid = threadIdx.x;
    for (int i = tid; i < 8 * 512; i += 384)
        rl[i] = __half2float(HS[(size_t)sb0 * 512 + i]);
    __syncthreads();
    int r = tid / TT, t = tid % TT;
    if (r < 8) {
        float acc = b_out[t];
        const float* rp = &rl[r * 512];
        #pragma unroll 8
        for (int k = 0; k < 512; k++)
            acc += rp[k] * WOT[k * TT + t];
        F[(size_t)(sb0 + r) * TT + t] = acc;
    }
}

// ---------------- Viterbi + backtrace: one wg per batch (fp32 exact) -------
__global__ __launch_bounds__(64) void k_viterbi(
    const float* __restrict__ F, const float* __restrict__ trans,
    float* __restrict__ out)
{
    int b = blockIdx.x;
    int tid = threadIdx.x;
    __shared__ float tl[TT * TT];        // transposed: tl[prev*T+next]
    __shared__ float fv[TT];
    __shared__ unsigned char bp[SS * TT];
    __shared__ unsigned char path[SS];
    for (int i = tid; i < TT * TT; i += 64) {
        int prev = i / TT, nx = i % TT;
        tl[i] = trans[nx * TT + prev];
    }
    if (tid < TT) fv[tid] = NEGV;
    __syncthreads();
    for (int s = 0; s < SS; s++) {
        float best = -1e30f; int bi = 0; float nf = 0.0f;
        if (tid < TT) {
            #pragma unroll 4
            for (int prev = 0; prev < TT; prev++) {
                float sc = fv[prev] + tl[prev * TT + tid];
                if (sc > best) { best = sc; bi = prev; }
            }
            nf = best + F[(size_t)(s * BB + b) * TT + tid];
            bp[s * TT + tid] = (unsigned char)bi;
        }
        __syncthreads();
        if (tid < TT) fv[tid] = nf;
        __syncthreads();
    }
    __syncthreads();
    if (tid == 0) {
        float best = fv[0]; int bi = 0;
        for (int i = 1; i < TT; i++) if (fv[i] > best) { best = fv[i]; bi = i; }
        out[b] = best;
        int tag = bi;
        path[SS - 1] = (unsigned char)tag;
        for (int j = SS - 2; j >= 0; j--) {
            tag = bp[(j + 1) * TT + tag];
            path[j] = (unsigned char)tag;
        }
    }
    __syncthreads();
    for (int j = tid; j < SS; j += 64)
        out[BB + (size_t)b * SS + j] = (float)path[j];
}

extern "C" void kernel_launch(void* const* d_in, const int* in_sizes, int n_in,
                              void* d_out, int out_size, void* d_ws, size_t ws_size,
                              hipStream_t stream) {
    const int*   wid    = (const int*)d_in[0];
    const int*   fid    = (const int*)d_in[1];
    const int*   pid    = (const int*)d_in[2];
    const float* ew     = (const float*)d_in[3];
    const float* ef     = (const float*)d_in[4];
    const float* epn    = (const float*)d_in[5];
    const float* Wih_f  = (const float*)d_in[6];
    const float* Whh_f  = (const float*)d_in[7];
    const float* bih_f  = (const float*)d_in[8];
    const float* bhh_f  = (const float*)d_in[9];
    const float* Wih_b  = (const float*)d_in[10];
    const float* Whh_b  = (const float*)d_in[11];
    const float* bih_b  = (const float*)d_in[12];
    const float* bhh_b  = (const float*)d_in[13];
    const float* h0     = (const float*)d_in[14];
    const float* c0     = (const float*)d_in[15];
    const float* W_out  = (const float*)d_in[16];
    const float* b_out  = (const float*)d_in[17];
    const float* trans  = (const float*)d_in[18];

    // ---- workspace carve (fp16 intermediates; total ≈ 198 MB) ----
    char* p = (char*)d_ws;
    auto alloc = [&](size_t bytes) { char* r = p; p += (bytes + 255) & ~(size_t)255; return r; };
    __half* X    = (__half*)alloc((size_t)32768 * EP * 2);   //  21.0 MB
    __half* GX   = (__half*)alloc((size_t)32768 * NG * 2);   // 134.2 MB
    __half* HS   = (__half*)alloc((size_t)32768 * 512 * 2);  //  33.6 MB
    __half* WTF  = (__half*)alloc((size_t)HH * G4 * 2);      //   0.5 MB
    __half* WTB  = (__half*)alloc((size_t)HH * G4 * 2);      //   0.5 MB
    __half* WIHT = (__half*)alloc((size_t)EP * NG * 2);      //   1.3 MB
    float*  BIAS = (float*)alloc((size_t)NG * 4);            //   8 KB
    float*  WOT  = (float*)alloc((size_t)512 * TT * 4);      //  98 KB
    float*  F    = (float*)alloc((size_t)32768 * TT * 4);    //   6.3 MB

    k_prep<<<4712, 256, 0, stream>>>(Whh_f, Whh_b, Wih_f, Wih_b,
                                     bih_f, bhh_f, bih_b, bhh_b, W_out,
                                     WTF, WTB, WIHT, BIAS, WOT);
    k_embed<<<32768, 320, 0, stream>>>(wid, fid, pid, ew, ef, epn, X);
    k_gemm<<<dim3(32, 512), 256, 0, stream>>>(X, WIHT, BIAS, GX);
    k_lstm<<<128, 256, 0, stream>>>(GX, WTF, WTB, h0, c0, HS);
    k_feats<<<4096, 384, 0, stream>>>(HS, WOT, b_out, F);
    k_viterbi<<<64, 64, 0, stream>>>(F, trans, (float*)d_out);
}

// Round 3
// 2589.935 us; speedup vs baseline: 2.6869x; 2.6869x over previous
//
#include <hip/hip_runtime.h>
#include <hip/hip_bf16.h>
#include <hip/hip_fp16.h>
#include <math.h>

#define BB 64
#define SS 512
#define TT 48
#define EE 300
#define EP 320   // E padded to multiple of 16
#define HH 256
#define G4 1024  // 4*H
#define NG 2048  // both directions
#define NEGV -10000.0f

// k_lstm weight split: 128 k-pairs per column total
//   96 pairs (192 k) in VGPRs  -> WPK, 48 uint4 per thread
//   32 pairs ( 64 k) in LDS    -> WPL, 16 uint4 per thread (128 KB LDS)
#define NREGC 12   // register chunks of 8 pairs
#define NLDSC 4    // LDS chunks of 8 pairs
#define WPK_U 98304   // uints per dir  (48*512*4)
#define WPL_U 32768   // uints per dir  (16*512*4)

__device__ __forceinline__ float sigf(float x) { return 1.0f / (1.0f + __expf(-x)); }

__device__ __forceinline__ float dot2u(unsigned int h, unsigned int w, float acc) {
#if __has_builtin(__builtin_amdgcn_fdot2)
    typedef _Float16 h2v __attribute__((ext_vector_type(2)));
    union { unsigned int u; h2v v; } H, W;
    H.u = h; W.u = w;
    return __builtin_amdgcn_fdot2(H.v, W.v, acc, false);
#else
    __half2 hh = *(__half2*)&h, ww = *(__half2*)&w;
    float2 hf = __half22float2(hh), wf = __half22float2(ww);
    return acc + hf.x * wf.x + hf.y * wf.y;
#endif
}

__device__ __forceinline__ unsigned int packh2(float lo, float hi) {
    union { __half2 h; unsigned int u; } p;
    p.h = __floats2half2_rn(lo, hi);
    return p.u;
}

__device__ __forceinline__ float4 ld_half4(const __half* p) {
    union { float2 f2; __half2 h2[2]; } u;
    u.f2 = *(const float2*)p;
    float2 a = __half22float2(u.h2[0]);
    float2 b = __half22float2(u.h2[1]);
    return make_float4(a.x, a.y, b.x, b.y);
}
__device__ __forceinline__ void st_half4(__half* p, float4 v) {
    union { float2 f2; __half2 h2[2]; } u;
    u.h2[0] = __floats2half2_rn(v.x, v.y);
    u.h2[1] = __floats2half2_rn(v.z, v.w);
    *(float2*)p = u.f2;
}

// ---------------- prep ----------------
// Gate-interleaved column order everywhere: col c = 4j+q  <->  source row q*256+j
// WIHT: [EP][NG] fp16, n = d*1024 + c (permuted)
// BIAS: [NG] fp32 (permuted, bih+bhh)
// WPK:  packed register weights, per dir 98304 uints
// WPL:  packed LDS weights,      per dir 32768 uints
// WOT:  [512][T] fp32
__global__ __launch_bounds__(256) void k_prep(
    const float* __restrict__ Whh_f, const float* __restrict__ Whh_b,
    const float* __restrict__ Wih_f, const float* __restrict__ Wih_b,
    const float* __restrict__ bih_f, const float* __restrict__ bhh_f,
    const float* __restrict__ bih_b, const float* __restrict__ bhh_b,
    const float* __restrict__ W_out,
    __half* __restrict__ WIHT, float* __restrict__ BIAS,
    unsigned int* __restrict__ WPK, unsigned int* __restrict__ WPL,
    float* __restrict__ WOT)
{
    int i = blockIdx.x * 256 + threadIdx.x;
    const int NWIH = EP * NG;      // 655360
    if (i < NWIH) {
        int k = i / NG, n = i % NG; int d = n >> 10, c = n & 1023;
        int row = (c & 3) * 256 + (c >> 2);
        const float* w = d ? Wih_b : Wih_f;
        WIHT[i] = __float2half((k < EE) ? w[row * EE + k] : 0.0f);
        return;
    }
    i -= NWIH;
    if (i < NG) {
        int d = i >> 10, c = i & 1023;
        int row = (c & 3) * 256 + (c >> 2);
        BIAS[i] = d ? (bih_b[row] + bhh_b[row]) : (bih_f[row] + bhh_f[row]);
        return;
    }
    i -= NG;
    if (i < 2 * WPK_U) {
        int d = i / WPK_U, uu = i % WPK_U;
        int r4 = uu / 2048, rem = uu % 2048, t = rem >> 2, rlo = rem & 3;
        int r = r4 * 4 + rlo, pi = r >> 1, cs = r & 1;
        int col = 2 * t + cs, k = 2 * pi;
        int row = (col & 3) * 256 + (col >> 2);
        const float* W = d ? Whh_b : Whh_f;
        WPK[i] = packh2(W[row * HH + k], W[row * HH + k + 1]);
        return;
    }
    i -= 2 * WPK_U;
    if (i < 2 * WPL_U) {
        int d = i / WPL_U, uu = i % WPL_U;
        int g = uu / 2048, rem = uu % 2048, t = rem >> 2, ii = rem & 3;
        int cs = g & 1, gs = g >> 1, c = gs >> 1, s = gs & 1;
        int p = 96 + c * 8 + s * 4 + ii;
        int col = 2 * t + cs, k = 2 * p;
        int row = (col & 3) * 256 + (col >> 2);
        const float* W = d ? Whh_b : Whh_f;
        WPL[i] = packh2(W[row * HH + k], W[row * HH + k + 1]);
        return;
    }
    i -= 2 * WPL_U;
    if (i < 512 * TT) { int k = i / TT, t = i % TT; WOT[i] = W_out[t * 512 + k]; return; }
}

// ---------------- embedding gather + concat + pad ----------------
__global__ __launch_bounds__(320) void k_embed(
    const int* __restrict__ wid, const int* __restrict__ fid, const int* __restrict__ pid,
    const float* __restrict__ ew, const float* __restrict__ ef, const float* __restrict__ ep,
    __half* __restrict__ X)
{
    int sb = blockIdx.x; int s = sb >> 6, b = sb & 63;
    int t = threadIdx.x;
    int w = wid[b * SS + s];
    int f = fid[b * SS + s];
    int p = pid[b * SS + s];
    float v;
    if (t < 200)      v = ew[w * 200 + t];
    else if (t < 250) v = ef[f * 50 + (t - 200)];
    else if (t < 300) v = ep[p * 50 + (t - 250)];
    else              v = 0.0f;
    X[(size_t)sb * EP + t] = __float2half(v);
}

// ---------------- input GEMM: GX[32768][2048] = X * WIHT + BIAS ----------
__global__ __launch_bounds__(256) void k_gemm(
    const __half* __restrict__ X, const __half* __restrict__ WIHT,
    const float* __restrict__ BIAS, __half* __restrict__ GX)
{
    __shared__ float Al[16][64];
    __shared__ float Bl[16][64];
    int tid = threadIdx.x;
    int tx = tid & 15, ty = tid >> 4;
    int m0 = blockIdx.y * 64, n0 = blockIdx.x * 64;
    float acc[4][4] = {};
    for (int k0 = 0; k0 < EP; k0 += 16) {
        int r = tid >> 2, q = tid & 3;
        float4 a4 = ld_half4(X + (size_t)(m0 + r) * EP + k0 + 4 * q);
        Al[4 * q + 0][r] = a4.x; Al[4 * q + 1][r] = a4.y;
        Al[4 * q + 2][r] = a4.z; Al[4 * q + 3][r] = a4.w;
        int kk = tid >> 4, c = (tid & 15) * 4;
        float4 b4 = ld_half4(WIHT + (size_t)(k0 + kk) * NG + n0 + c);
        *(float4*)&Bl[kk][c] = b4;
        __syncthreads();
        #pragma unroll
        for (int k = 0; k < 16; k++) {
            float4 a = *(const float4*)&Al[k][ty * 4];
            float4 b = *(const float4*)&Bl[k][tx * 4];
            acc[0][0] += a.x * b.x; acc[0][1] += a.x * b.y; acc[0][2] += a.x * b.z; acc[0][3] += a.x * b.w;
            acc[1][0] += a.y * b.x; acc[1][1] += a.y * b.y; acc[1][2] += a.y * b.z; acc[1][3] += a.y * b.w;
            acc[2][0] += a.z * b.x; acc[2][1] += a.z * b.y; acc[2][2] += a.z * b.z; acc[2][3] += a.z * b.w;
            acc[3][0] += a.w * b.x; acc[3][1] += a.w * b.y; acc[3][2] += a.w * b.z; acc[3][3] += a.w * b.w;
        }
        __syncthreads();
    }
    float4 bias = *(const float4*)(BIAS + n0 + tx * 4);
    #pragma unroll
    for (int i = 0; i < 4; i++) {
        float4 st;
        st.x = acc[i][0] + bias.x; st.y = acc[i][1] + bias.y;
        st.z = acc[i][2] + bias.z; st.w = acc[i][3] + bias.w;
        st_half4(GX + (size_t)(m0 + ty * 4 + i) * NG + n0 + tx * 4, st);
    }
}

// ---------------- recurrent LSTM: weights resident in VGPR+LDS ----------
// 128 wgs (dir,b), 512 threads. Thread owns gate cols c0=2tid, c1=2tid+1
// (interleaved layout: cols 4j+{0,1,2,3} = i,f,g,o of hidden j).
__global__ __launch_bounds__(512, 2) void k_lstm(
    const uint4* __restrict__ WPK, const uint4* __restrict__ WPL,
    const __half* __restrict__ GX, const float* __restrict__ h0,
    const float* __restrict__ c0, __half* __restrict__ HS)
{
    __shared__ uint4 LW[16 * 512];                 // 128 KB LDS-resident weights
    __shared__ __align__(16) __half hl[HH];        // h broadcast buffer
    int wg = blockIdx.x; int dir = wg >> 6, b = wg & 63;
    int tid = threadIdx.x;
    int j = tid >> 1;

    // load register-resident weights (coalesced: [r4][tid] layout)
    const uint4* wpk = WPK + (size_t)dir * (48 * 512);
    uint4 WR[48];
    #pragma unroll
    for (int r4 = 0; r4 < 48; r4++) WR[r4] = wpk[r4 * 512 + tid];

    // stage LDS-resident weights
    const uint4* wpl = WPL + (size_t)dir * (16 * 512);
    #pragma unroll
    for (int g = 0; g < 16; g++) LW[g * 512 + tid] = wpl[g * 512 + tid];

    float c = 0.0f;
    if ((tid & 1) == 0) {
        hl[j] = __float2half(h0[(size_t)dir * BB * HH + b * HH + j]);
        c = c0[(size_t)dir * BB * HH + b * HH + j];
    }
    __syncthreads();

    for (int t = 0; t < SS; t++) {
        int s = dir ? (SS - 1 - t) : t;
        size_t row = (size_t)(s * BB + b);
        unsigned int gxv = *(const unsigned int*)(GX + row * NG + (dir << 10) + 2 * tid);
        __half2 gh = *(__half2*)&gxv;
        float2 gf = __half22float2(gh);
        float a0 = gf.x, a1 = gf.y;

        // register-weight chunks: pairs 0..95
        #pragma unroll
        for (int ch = 0; ch < NREGC; ch++) {
            uint4 hA = *(const uint4*)&hl[ch * 16];
            uint4 hB = *(const uint4*)&hl[ch * 16 + 8];
            uint4 q0 = WR[ch * 4 + 0], q1 = WR[ch * 4 + 1];
            uint4 q2 = WR[ch * 4 + 2], q3 = WR[ch * 4 + 3];
            a0 = dot2u(hA.x, q0.x, a0); a1 = dot2u(hA.x, q0.y, a1);
            a0 = dot2u(hA.y, q0.z, a0); a1 = dot2u(hA.y, q0.w, a1);
            a0 = dot2u(hA.z, q1.x, a0); a1 = dot2u(hA.z, q1.y, a1);
            a0 = dot2u(hA.w, q1.z, a0); a1 = dot2u(hA.w, q1.w, a1);
            a0 = dot2u(hB.x, q2.x, a0); a1 = dot2u(hB.x, q2.y, a1);
            a0 = dot2u(hB.y, q2.z, a0); a1 = dot2u(hB.y, q2.w, a1);
            a0 = dot2u(hB.z, q3.x, a0); a1 = dot2u(hB.z, q3.y, a1);
            a0 = dot2u(hB.w, q3.z, a0); a1 = dot2u(hB.w, q3.w, a1);
        }
        // LDS-weight chunks: pairs 96..127
        #pragma unroll
        for (int lc = 0; lc < NLDSC; lc++) {
            int ch = NREGC + lc;
            uint4 hA = *(const uint4*)&hl[ch * 16];
            uint4 hB = *(const uint4*)&hl[ch * 16 + 8];
            uint4 u0 = LW[((lc * 2 + 0) * 2 + 0) * 512 + tid];
            uint4 u1 = LW[((lc * 2 + 0) * 2 + 1) * 512 + tid];
            uint4 u2 = LW[((lc * 2 + 1) * 2 + 0) * 512 + tid];
            uint4 u3 = LW[((lc * 2 + 1) * 2 + 1) * 512 + tid];
            a0 = dot2u(hA.x, u0.x, a0); a1 = dot2u(hA.x, u1.x, a1);
            a0 = dot2u(hA.y, u0.y, a0); a1 = dot2u(hA.y, u1.y, a1);
            a0 = dot2u(hA.z, u0.z, a0); a1 = dot2u(hA.z, u1.z, a1);
            a0 = dot2u(hA.w, u0.w, a0); a1 = dot2u(hA.w, u1.w, a1);
            a0 = dot2u(hB.x, u2.x, a0); a1 = dot2u(hB.x, u3.x, a1);
            a0 = dot2u(hB.y, u2.y, a0); a1 = dot2u(hB.y, u3.y, a1);
            a0 = dot2u(hB.z, u2.z, a0); a1 = dot2u(hB.z, u3.z, a1);
            a0 = dot2u(hB.w, u2.w, a0); a1 = dot2u(hB.w, u3.w, a1);
        }
        __syncthreads();   // all hl reads done
        float pg = __shfl_xor(a0, 1);
        float po = __shfl_xor(a1, 1);
        if ((tid & 1) == 0) {
            // a0=i_pre, a1=f_pre, pg=g_pre, po=o_pre
            c = sigf(a1) * c + sigf(a0) * tanhf(pg);
            float h = sigf(po) * tanhf(c);
            __half hh = __float2half(h);
            hl[j] = hh;
            HS[row * 512 + (dir << 8) + j] = hh;
        }
        __syncthreads();
    }
}

// ---------------- feats: [32768][48] = HS * WOT + b_out ------------------
__global__ __launch_bounds__(384) void k_feats(
    const __half* __restrict__ HS, const float* __restrict__ WOT,
    const float* __restrict__ b_out, float* __restrict__ F)
{
    __shared__ float rl[8 * 512];
    int sb0 = blockIdx.x * 8;
    int tid = threadIdx.x;
    for (int i = tid; i < 8 * 512; i += 384)
        rl[i] = __half2float(HS[(size_t)sb0 * 512 + i]);
    __syncthreads();
    int r = tid / TT, t = tid % TT;
    if (r < 8) {
        float acc = b_out[t];
        const float* rp = &rl[r * 512];
        #pragma unroll 8
        for (int k = 0; k < 512; k++)
            acc += rp[k] * WOT[k * TT + t];
        F[(size_t)(sb0 + r) * TT + t] = acc;
    }
}

// ---------------- Viterbi + backtrace: one wg per batch ------------------
__global__ __launch_bounds__(64) void k_viterbi(
    const float* __restrict__ F, const float* __restrict__ trans,
    float* __restrict__ out)
{
    int b = blockIdx.x;
    int tid = threadIdx.x;
    __shared__ float tl[TT * TT];        // transposed: tl[prev*T+next]
    __shared__ float fv[TT];
    __shared__ unsigned char bp[SS * TT];
    __shared__ unsigned char path[SS];
    for (int i = tid; i < TT * TT; i += 64) {
        int prev = i / TT, nx = i % TT;
        tl[i] = trans[nx * TT + prev];
    }
    if (tid < TT) fv[tid] = NEGV;
    __syncthreads();
    for (int s = 0; s < SS; s++) {
        float best = -1e30f; int bi = 0; float nf = 0.0f;
        if (tid < TT) {
            #pragma unroll 4
            for (int prev = 0; prev < TT; prev++) {
                float sc = fv[prev] + tl[prev * TT + tid];
                if (sc > best) { best = sc; bi = prev; }
            }
            nf = best + F[(size_t)(s * BB + b) * TT + tid];
            bp[s * TT + tid] = (unsigned char)bi;
        }
        __syncthreads();
        if (tid < TT) fv[tid] = nf;
        __syncthreads();
    }
    if (tid == 0) {
        float best = fv[0]; int bi = 0;
        for (int i = 1; i < TT; i++) if (fv[i] > best) { best = fv[i]; bi = i; }
        out[b] = best;
        int tag = bi;
        path[SS - 1] = (unsigned char)tag;
        for (int jj = SS - 2; jj >= 0; jj--) {
            tag = bp[(jj + 1) * TT + tag];
            path[jj] = (unsigned char)tag;
        }
    }
    __syncthreads();
    for (int jj = tid; jj < SS; jj += 64)
        out[BB + (size_t)b * SS + jj] = (float)path[jj];
}

extern "C" void kernel_launch(void* const* d_in, const int* in_sizes, int n_in,
                              void* d_out, int out_size, void* d_ws, size_t ws_size,
                              hipStream_t stream) {
    const int*   wid    = (const int*)d_in[0];
    const int*   fid    = (const int*)d_in[1];
    const int*   pid    = (const int*)d_in[2];
    const float* ew     = (const float*)d_in[3];
    const float* ef     = (const float*)d_in[4];
    const float* epn    = (const float*)d_in[5];
    const float* Wih_f  = (const float*)d_in[6];
    const float* Whh_f  = (const float*)d_in[7];
    const float* bih_f  = (const float*)d_in[8];
    const float* bhh_f  = (const float*)d_in[9];
    const float* Wih_b  = (const float*)d_in[10];
    const float* Whh_b  = (const float*)d_in[11];
    const float* bih_b  = (const float*)d_in[12];
    const float* bhh_b  = (const float*)d_in[13];
    const float* h0     = (const float*)d_in[14];
    const float* c0     = (const float*)d_in[15];
    const float* W_out  = (const float*)d_in[16];
    const float* b_out  = (const float*)d_in[17];
    const float* trans  = (const float*)d_in[18];

    char* p = (char*)d_ws;
    auto alloc = [&](size_t bytes) { char* r = p; p += (bytes + 255) & ~(size_t)255; return r; };
    __half*       X    = (__half*)alloc((size_t)32768 * EP * 2);    //  21.0 MB
    __half*       GX   = (__half*)alloc((size_t)32768 * NG * 2);    // 134.2 MB
    __half*       HS   = (__half*)alloc((size_t)32768 * 512 * 2);   //  33.6 MB
    unsigned int* WPK  = (unsigned int*)alloc((size_t)2 * WPK_U * 4); // 0.79 MB
    unsigned int* WPL  = (unsigned int*)alloc((size_t)2 * WPL_U * 4); // 0.26 MB
    __half*       WIHT = (__half*)alloc((size_t)EP * NG * 2);       //   1.3 MB
    float*        BIAS = (float*)alloc((size_t)NG * 4);             //   8 KB
    float*        WOT  = (float*)alloc((size_t)512 * TT * 4);       //  98 KB
    float*        F    = (float*)alloc((size_t)32768 * TT * 4);     //   6.3 MB

    // k_prep elements: 655360 + 2048 + 196608 + 65536 + 24576 = 944128
    k_prep<<<3688, 256, 0, stream>>>(Whh_f, Whh_b, Wih_f, Wih_b,
                                     bih_f, bhh_f, bih_b, bhh_b, W_out,
                                     WIHT, BIAS, WPK, WPL, WOT);
    k_embed<<<32768, 320, 0, stream>>>(wid, fid, pid, ew, ef, epn, X);
    k_gemm<<<dim3(32, 512), 256, 0, stream>>>(X, WIHT, BIAS, GX);
    k_lstm<<<128, 512, 0, stream>>>((const uint4*)WPK, (const uint4*)WPL,
                                    GX, h0, c0, HS);
    k_feats<<<4096, 384, 0, stream>>>(HS, WOT, b_out, F);
    k_viterbi<<<64, 64, 0, stream>>>(F, trans, (float*)d_out);
}